// Round 6
// baseline (263.704 us; speedup 1.0000x reference)
//
#include <hip/hip_runtime.h>

// MHAttention B=8 T=2048 C=512 H=512, causal, fp32 in/out.
// cast(fp32->fp16) -> fused QKV GEMM (Q,K row-major; V in MFMA-frag layout) -> flash.
// R6 flash: swapped QK^T (mfma(K,Q)) with per-lane softmax (R5-verified layouts);
// K staged global->LDS (contiguous, prefetched mid-step, XOR row&31 swizzle);
// Q in registers; V loads contiguous via fragment-ordered Vt layout.

using short8 = __attribute__((ext_vector_type(8))) short;
using half8  = __attribute__((ext_vector_type(8))) _Float16;
using f32x4  = __attribute__((ext_vector_type(4))) float;
using f32x16 = __attribute__((ext_vector_type(16))) float;

#define B_    8
#define T_    2048
#define SCALE_ 0.044194173824159216f   // 512^-0.5

// flash LDS: K [128][512] f16 (1KB rows, 16B-granule XOR row&31) at 0
#define FL_P    131072   // [64 q][128 kv] f16, 16B-granule XOR (q&7): 16 KB
#define FL_STX  147456   // [64 q][4 ks] f32 tile-max partials
#define FL_STS  148480   // [64 q][4 ks] f32 tile-sum partials
#define FL_SMEM 149504
// epilogue scratch reuses K region: per wave 32 rows x 144B at wv*4608

__device__ __forceinline__ void gload_lds16(const void* g, void* l) {
  __builtin_amdgcn_global_load_lds(
      (const __attribute__((address_space(1))) unsigned int*)g,
      (__attribute__((address_space(3))) unsigned int*)l, 16, 0, 0);
}

__device__ __forceinline__ unsigned short f2h(float f) {  // RNE f32->f16 bits
  _Float16 h = (_Float16)f;
  return *(unsigned short*)&h;
}

// barrier waiting only on LDS ops — global loads / global_load_lds (vmcnt) stay in flight
__device__ __forceinline__ void barrier_lgkm() {
  asm volatile("s_waitcnt lgkmcnt(0)" ::: "memory");
  __builtin_amdgcn_s_barrier();
  asm volatile("" ::: "memory");
}

// ---------------------------------------------------------------- cast kernel
__global__ __launch_bounds__(256) void cast_kernel(
    const float* __restrict__ x, const float* __restrict__ wq,
    const float* __restrict__ wk, const float* __restrict__ wv,
    unsigned short* __restrict__ xb, unsigned short* __restrict__ wcat) {
  size_t i4 = (size_t)blockIdx.x * 256 + threadIdx.x;   // one float4 per thread
  const size_t NX4 = (size_t)(B_ * T_ * 512) / 4;       // 2097152
  const float* src; unsigned short* dst; size_t off4;
  if (i4 < NX4) { src = x; dst = xb; off4 = i4; }
  else {
    size_t w4 = i4 - NX4;                 // < 196608
    size_t mat = w4 >> 16;                // 65536 float4 per 512x512 matrix
    off4 = w4 & 65535;
    src = (mat == 0) ? wq : (mat == 1) ? wk : wv;
    dst = wcat + (mat << 18);
  }
  float4 v = ((const float4*)src)[off4];
  unsigned long long pk = (unsigned long long)f2h(v.x)
                        | ((unsigned long long)f2h(v.y) << 16)
                        | ((unsigned long long)f2h(v.z) << 32)
                        | ((unsigned long long)f2h(v.w) << 48);
  *(unsigned long long*)(dst + off4 * 4) = pk;
}

// ---------------------------------------------------------------- QKV GEMM
// C[m][n] = sum_k xb[m][k] * wcat[n][k],  M=16384, N=1536, K=512.
// 128x128 tile, BK=64, 4 waves (2x2), 16x16x32 f16 MFMA, double-buffered LDS.
// V output written in flash fragment order: 16B block (d-major) index
// ((b*16 + kvt)*16 + (s*2+h))*512 + d  where t = kvt*128 + s*16 + h*8 + j.
__device__ __forceinline__ void gemm_stage(
    const unsigned short* __restrict__ xb, const unsigned short* __restrict__ wcat,
    char* smem, int buf, int mbase, int nbase, int kt, int wv, int lane, int srcg) {
  char* base = smem + buf * 32768;
  const int kbase = kt * 64;
  if (wv < 2) {
    #pragma unroll
    for (int i = 0; i < 8; ++i) {
      const int blk = wv * 8 + i;
      const int row = blk * 8 + (lane >> 3);
      gload_lds16(xb + (size_t)(mbase + row) * 512 + kbase + srcg, base + blk * 1024);
    }
  } else {
    #pragma unroll
    for (int i = 0; i < 8; ++i) {
      const int blk = (wv - 2) * 8 + i;
      const int row = blk * 8 + (lane >> 3);
      gload_lds16(wcat + (size_t)(nbase + row) * 512 + kbase + srcg, base + 16384 + blk * 1024);
    }
  }
}

__global__ __launch_bounds__(256, 2) void gemm_qkv(
    const unsigned short* __restrict__ xb, const unsigned short* __restrict__ wcat,
    unsigned short* __restrict__ Qb, unsigned short* __restrict__ Kb,
    unsigned short* __restrict__ Vtb) {
  __shared__ char smem[65536];
  const int tid = threadIdx.x, lane = tid & 63, wv = tid >> 6;
  const int wr = wv >> 1, wc = wv & 1;
  const int l15 = lane & 15, l4 = lane >> 4;
  const int mbase = blockIdx.x * 128;
  const int nbase = blockIdx.y * 128;
  const int srcg = (((lane & 7) ^ ((lane >> 3) & 7))) * 8;

  f32x4 acc[4][4];
  #pragma unroll
  for (int i = 0; i < 4; ++i)
    #pragma unroll
    for (int j = 0; j < 4; ++j) acc[i][j] = (f32x4){0.f, 0.f, 0.f, 0.f};

  gemm_stage(xb, wcat, smem, 0, mbase, nbase, 0, wv, lane, srcg);
  for (int kt = 0; kt < 8; ++kt) {
    __syncthreads();
    if (kt < 7) gemm_stage(xb, wcat, smem, (kt + 1) & 1, mbase, nbase, kt + 1, wv, lane, srcg);
    const char* base = smem + (kt & 1) * 32768;
    #pragma unroll
    for (int ks = 0; ks < 2; ++ks) {
      half8 a[4], b8[4];
      #pragma unroll
      for (int rt = 0; rt < 4; ++rt) {
        const int row = wr * 64 + rt * 16 + l15;
        const int G = (ks * 4 + l4) ^ (row & 7);
        a[rt] = *(const half8*)(base + row * 128 + G * 16);
      }
      #pragma unroll
      for (int ct = 0; ct < 4; ++ct) {
        const int row = wc * 64 + ct * 16 + l15;
        const int G = (ks * 4 + l4) ^ (row & 7);
        b8[ct] = *(const half8*)(base + 16384 + row * 128 + G * 16);
      }
      #pragma unroll
      for (int rt = 0; rt < 4; ++rt)
        #pragma unroll
        for (int ct = 0; ct < 4; ++ct)
          acc[rt][ct] = __builtin_amdgcn_mfma_f32_16x16x32_f16(a[rt], b8[ct], acc[rt][ct], 0, 0, 0);
    }
  }

  const int mat = nbase >> 9;          // 0=Q, 1=K, 2=V
  const int nloc = nbase & 511;
  if (mat < 2) {
    unsigned short* O = (mat == 0) ? Qb : Kb;
    #pragma unroll
    for (int rt = 0; rt < 4; ++rt)
      #pragma unroll
      for (int ct = 0; ct < 4; ++ct) {
        const int m0 = mbase + wr * 64 + rt * 16 + l4 * 4;
        const int n = nloc + wc * 64 + ct * 16 + l15;
        #pragma unroll
        for (int j = 0; j < 4; ++j)
          O[(size_t)(m0 + j) * 512 + n] = f2h(acc[rt][ct][j]);
      }
  } else {
    // V in flash fragment order (see header comment); j..j+3 stay in one block
    #pragma unroll
    for (int rt = 0; rt < 4; ++rt)
      #pragma unroll
      for (int ct = 0; ct < 4; ++ct) {
        const int m0 = mbase + wr * 64 + rt * 16 + l4 * 4;
        const int d = nloc + wc * 64 + ct * 16 + l15;
        const int bb = m0 >> 11, t = m0 & 2047;
        const int kvt = t >> 7, u = (t >> 3) & 15, jj = t & 7;
        unsigned long long pk = (unsigned long long)f2h(acc[rt][ct][0])
                              | ((unsigned long long)f2h(acc[rt][ct][1]) << 16)
                              | ((unsigned long long)f2h(acc[rt][ct][2]) << 32)
                              | ((unsigned long long)f2h(acc[rt][ct][3]) << 48);
        *(unsigned long long*)(Vtb + ((((size_t)bb * 16 + kvt) * 16 + u) * 512 + d) * 8 + jj) = pk;
      }
  }
}

// ---------------------------------------------------------------- flash attention
// 256 WGs x 8 waves; b = blk&7 (XCD), qt = 31-(blk>>3) (64 q-rows, long first).
// nkv = (qt+2)>>1 steps of KVBLK=128.
// QK role: wave (qg=wv&1, ks=wv>>1): S^T strip = mfma32(K_lds, qf_regs), full D.
// PV role: wave owns d strip [wv*64..+64): O^T += mfma32(V_frag_global, P_lds).
// Per step: sync(K staged) -> QK -> mask/max -> lgkmB -> stage K_next (async) ->
//   vf0 loads, softmax, P+sts -> lgkmC -> alpha/l, rescale, vf1, PV.
__device__ __forceinline__ void stage_k(const unsigned short* __restrict__ Kb,
                                        char* smem, size_t bT, int kvt,
                                        int wv, int lane) {
  const unsigned short* src = Kb + (bT + (size_t)kvt * 128) * 512;
  #pragma unroll
  for (int i = 0; i < 16; ++i) {
    const int r = wv * 16 + i;                      // 128 rows x 1KB
    gload_lds16(src + (size_t)r * 512 + ((lane ^ (r & 31)) * 8), smem + r * 1024);
  }
}

__global__ __launch_bounds__(512, 1) void flash_kernel(
    const unsigned short* __restrict__ Qb, const unsigned short* __restrict__ Kb,
    const unsigned short* __restrict__ Vtb, float* __restrict__ out) {
  extern __shared__ char smem[];
  float* stx = (float*)(smem + FL_STX);
  float* sts = (float*)(smem + FL_STS);

  const int tid = threadIdx.x, lane = tid & 63, wv = tid >> 6;
  const int l31 = lane & 31, h = lane >> 5;
  const int qg = wv & 1, ks = wv >> 1;             // QK role
  const int dh = wv;                               // PV role d-strip
  const int qsw = l31 & 7;
  const int b = blockIdx.x & 7;                    // batch == XCD
  const int qt = 31 - (blockIdx.x >> 3);           // long tiles first
  const size_t bT = (size_t)b * T_;
  const int nkv = (qt + 2) >> 1;

  // Q -> registers: B-frag layout (lane l31 = q col of qg half, h = k-half)
  half8 qf[32];
  {
    const unsigned short* qp = Qb + (bT + (size_t)qt * 64 + qg * 32 + l31) * 512 + h * 8;
    #pragma unroll
    for (int s = 0; s < 32; ++s) qf[s] = *(const half8*)(qp + s * 16);
  }

  f32x16 o[2][2];                                  // o[dt][q2]: O^T [32 d][32 q]
  #pragma unroll
  for (int dt = 0; dt < 2; ++dt)
    #pragma unroll
    for (int q2 = 0; q2 < 2; ++q2)
      #pragma unroll
      for (int r = 0; r < 16; ++r) o[dt][q2][r] = 0.f;
  float lreg[2] = {0.f, 0.f};
  float mqpv[2] = {-1e30f, -1e30f};
  float mqk = -1e30f;

  stage_k(Kb, smem, bT, 0, wv, lane);

  for (int kv = 0; kv < nkv; ++kv) {
    const int kv0 = kv * 128;
    __syncthreads();                               // K[kv] staged (vmcnt drained)

    // ---- QK^T swapped: acc = S^T[32 kv strip][32 q], full D, K from LDS ----
    f32x16 acc;
    #pragma unroll
    for (int r = 0; r < 16; ++r) acc[r] = 0.f;
    {
      const int krow = ks * 32 + l31;
      const char* kb = smem + krow * 1024;
      const int ksw = krow & 31;
      #pragma unroll
      for (int s = 0; s < 32; ++s) {
        half8 kf = *(const half8*)(kb + (((s * 2 + h) ^ ksw) << 4));
        acc = __builtin_amdgcn_mfma_f32_32x32x16_f16(kf, qf[s], acc, 0, 0, 0);
      }
    }

    // ---- scale + causal mask + in-lane strip max ----
    float v[16], tm = -1e30f;
    const int qglob = qt * 64 + qg * 32 + l31;
    #pragma unroll
    for (int r = 0; r < 16; ++r) {
      const int kvg = kv0 + ks * 32 + (r & 3) + 8 * (r >> 2) + 4 * h;
      v[r] = (kvg <= qglob) ? acc[r] * SCALE_ : -1e30f;
      tm = fmaxf(tm, v[r]);
    }
    tm = fmaxf(tm, __shfl_xor(tm, 32, 64));
    if (h == 0) stx[(qg * 32 + l31) * 4 + ks] = tm;
    barrier_lgkm();                                // B: strip maxes visible; K reads done

    if (kv + 1 < nkv) stage_k(Kb, smem, bT, kv + 1, wv, lane);  // async prefetch

    // ---- V frags half 0 (s=0..3): contiguous fragment-order loads ----
    const size_t vblk = ((size_t)b * 16 + kv) * 16;
    half8 vf0[4][2];
    #pragma unroll
    for (int s = 0; s < 4; ++s)
      #pragma unroll
      for (int dt = 0; dt < 2; ++dt)
        vf0[s][dt] = *(const half8*)(
            Vtb + ((vblk + s * 2 + h) * 512 + dh * 64 + dt * 32 + l31) * 8);

    // ---- softmax (per-lane scalar state) ----
    {
      const f32x4 sx = *(const f32x4*)(stx + (qg * 32 + l31) * 4);
      const float mn = fmaxf(fmaxf(fmaxf(sx[0], sx[1]), fmaxf(sx[2], sx[3])), mqk);
      mqk = mn;
      unsigned short ph[16];
      float ps = 0.f;
      #pragma unroll
      for (int r = 0; r < 16; ++r) {
        const float p = __expf(v[r] - mn);
        ph[r] = f2h(p);                            // round first; sum the rounded
        ps += (float)*(const _Float16*)&ph[r];
      }
      ps += __shfl_xor(ps, 32, 64);
      if (h == 0) sts[(qg * 32 + l31) * 4 + ks] = ps;
      #pragma unroll
      for (int c = 0; c < 4; ++c) {                // P -> LDS, b64 packed
        const unsigned long long pk =
            (unsigned long long)ph[4 * c]
          | ((unsigned long long)ph[4 * c + 1] << 16)
          | ((unsigned long long)ph[4 * c + 2] << 32)
          | ((unsigned long long)ph[4 * c + 3] << 48);
        *(unsigned long long*)(smem + FL_P + (qg * 32 + l31) * 256 +
                               ((((ks * 4 + c) ^ qsw)) << 4) + h * 8) = pk;
      }
    }
    barrier_lgkm();                                // C: P + stats visible

    // ---- per-lane alpha/l update, rescale O ----
    #pragma unroll
    for (int q2 = 0; q2 < 2; ++q2) {
      const f32x4 sx2 = *(const f32x4*)(stx + (q2 * 32 + l31) * 4);
      float mn2 = fmaxf(fmaxf(sx2[0], sx2[1]), fmaxf(sx2[2], sx2[3]));
      mn2 = fmaxf(mn2, mqpv[q2]);
      const float a = __expf(mqpv[q2] - mn2);
      mqpv[q2] = mn2;
      const f32x4 s4 = *(const f32x4*)(sts + (q2 * 32 + l31) * 4);
      lreg[q2] = a * lreg[q2] + ((s4[0] + s4[1]) + (s4[2] + s4[3]));
      #pragma unroll
      for (int dt = 0; dt < 2; ++dt)
        #pragma unroll
        for (int r = 0; r < 16; ++r) o[dt][q2][r] *= a;
    }

    // ---- V frags half 1 (s=4..7) ----
    half8 vf1[4][2];
    #pragma unroll
    for (int s = 0; s < 4; ++s)
      #pragma unroll
      for (int dt = 0; dt < 2; ++dt)
        vf1[s][dt] = *(const half8*)(
            Vtb + ((vblk + (s + 4) * 2 + h) * 512 + dh * 64 + dt * 32 + l31) * 8);

    // ---- PV: O^T += Vt x P ----
    #pragma unroll
    for (int s = 0; s < 8; ++s) {
      half8 pa[2];
      #pragma unroll
      for (int q2 = 0; q2 < 2; ++q2)
        pa[q2] = *(const half8*)(smem + FL_P + (q2 * 32 + l31) * 256 +
                                 (((s * 2 + h) ^ qsw) << 4));
      #pragma unroll
      for (int dt = 0; dt < 2; ++dt) {
        const half8 vfr = (s < 4) ? vf0[s][dt] : vf1[s - 4][dt];
        #pragma unroll
        for (int q2 = 0; q2 < 2; ++q2)
          o[dt][q2] = __builtin_amdgcn_mfma_f32_32x32x16_f16(vfr, pa[q2], o[dt][q2], 0, 0, 0);
      }
    }
  }

  // ---- epilogue: transpose O^T via per-wave scratch (K region is dead), ----
  // ---- divide by l, coalesced 128B stores ----
  {
    char* scr = smem + wv * 4608;                  // 32 rows x 144B
    const float linv[2] = {1.0f / lreg[0], 1.0f / lreg[1]};
    #pragma unroll
    for (int q2 = 0; q2 < 2; ++q2)
      #pragma unroll
      for (int dt = 0; dt < 2; ++dt) {
        #pragma unroll
        for (int c = 0; c < 4; ++c) {
          f32x4 w4;
          #pragma unroll
          for (int j = 0; j < 4; ++j) w4[j] = o[dt][q2][4 * c + j] * linv[q2];
          *(f32x4*)(scr + l31 * 144 + c * 32 + h * 16) = w4;   // scr[q][d]
        }
        asm volatile("s_waitcnt lgkmcnt(0)" ::: "memory");
        #pragma unroll
        for (int g = 0; g < 4; ++g) {
          const int qr = g * 8 + (lane >> 3);
          const f32x4 r4 = *(const f32x4*)(scr + qr * 144 + (lane & 7) * 16);
          *(f32x4*)(out + (bT + qt * 64 + q2 * 32 + qr) * 512 +
                    dh * 64 + dt * 32 + (lane & 7) * 4) = r4;
        }
        asm volatile("s_waitcnt lgkmcnt(0)" ::: "memory");
      }
  }
}

// ---------------------------------------------------------------- launch
extern "C" void kernel_launch(void* const* d_in, const int* in_sizes, int n_in,
                              void* d_out, int out_size, void* d_ws, size_t ws_size,
                              hipStream_t stream) {
  (void)in_sizes; (void)n_in; (void)out_size; (void)ws_size;
  const float* x  = (const float*)d_in[0];
  const float* wq = (const float*)d_in[1];
  const float* wk = (const float*)d_in[2];
  const float* wv = (const float*)d_in[3];
  float* out = (float*)d_out;

  unsigned short* ws   = (unsigned short*)d_ws;
  unsigned short* xb   = ws;                                    // [16384][512]
  unsigned short* wcat = xb + (size_t)16384 * 512;              // [1536][512]
  unsigned short* Qb   = wcat + (size_t)1536 * 512;             // [16384][512]
  unsigned short* Kb   = Qb + (size_t)16384 * 512;              // [16384][512]
  unsigned short* Vtb  = Kb + (size_t)16384 * 512;              // [8][16][16][512][8] frag order
  // total ws use: 68.7 MB

  cast_kernel<<<8960, 256, 0, stream>>>(x, wq, wk, wv, xb, wcat);
  gemm_qkv<<<dim3(128, 12), 256, 0, stream>>>(xb, wcat, Qb, Kb, Vtb);
  hipFuncSetAttribute(reinterpret_cast<const void*>(flash_kernel),
                      hipFuncAttributeMaxDynamicSharedMemorySize, FL_SMEM);
  flash_kernel<<<256, 512, FL_SMEM, stream>>>(Qb, Kb, Vtb, out);
}

// Round 7
// 144.127 us; speedup vs baseline: 1.8297x; 1.8297x over previous
//
#include <hip/hip_runtime.h>

// MHAttention B=8 T=2048 C=512 H=512, causal, fp32 in/out.
// cast(fp32->fp16) -> fused QKV GEMM (Q row-major; K,V in MFMA-frag order) -> flash.
// R7 flash: Q in LDS (staged once, read as B-frags per step); K frag-order
// global -> transient regs (contiguous 1KB/wave loads, dead after QK);
// V frag-order global (R6); P/stx/sts double-buffered -> 2 lgkm barriers/step,
// no vmcnt drains, no in-loop LDS staging.

using short8 = __attribute__((ext_vector_type(8))) short;
using half8  = __attribute__((ext_vector_type(8))) _Float16;
using f32x4  = __attribute__((ext_vector_type(4))) float;
using f32x16 = __attribute__((ext_vector_type(16))) float;

#define B_    8
#define T_    2048
#define SCALE_ 0.044194173824159216f   // 512^-0.5

// flash LDS: Q [64 rows][1KB] f16 (16B-granule XOR row&31) at 0
#define FL_P    65536    // 2 x [64 q][256B] f16 (granule XOR row&7), parity-buffered
#define FL_STX  98304    // 2 x [64 q][4 ks] f32
#define FL_STS  100352   // 2 x [64 q][4 ks] f32
#define FL_SMEM 102400
// epilogue scratch reuses Q region (per wave 32 x 144B at wv*4608)

__device__ __forceinline__ void gload_lds16(const void* g, void* l) {
  __builtin_amdgcn_global_load_lds(
      (const __attribute__((address_space(1))) unsigned int*)g,
      (__attribute__((address_space(3))) unsigned int*)l, 16, 0, 0);
}

__device__ __forceinline__ unsigned short f2h(float f) {  // RNE f32->f16 bits
  _Float16 h = (_Float16)f;
  return *(unsigned short*)&h;
}

// barrier waiting only on LDS ops — global loads (vmcnt) stay in flight
__device__ __forceinline__ void barrier_lgkm() {
  asm volatile("s_waitcnt lgkmcnt(0)" ::: "memory");
  __builtin_amdgcn_s_barrier();
  asm volatile("" ::: "memory");
}

// ---------------------------------------------------------------- cast kernel
__global__ __launch_bounds__(256) void cast_kernel(
    const float* __restrict__ x, const float* __restrict__ wq,
    const float* __restrict__ wk, const float* __restrict__ wv,
    unsigned short* __restrict__ xb, unsigned short* __restrict__ wcat) {
  size_t i4 = (size_t)blockIdx.x * 256 + threadIdx.x;   // one float4 per thread
  const size_t NX4 = (size_t)(B_ * T_ * 512) / 4;       // 2097152
  const float* src; unsigned short* dst; size_t off4;
  if (i4 < NX4) { src = x; dst = xb; off4 = i4; }
  else {
    size_t w4 = i4 - NX4;                 // < 196608
    size_t mat = w4 >> 16;                // 65536 float4 per 512x512 matrix
    off4 = w4 & 65535;
    src = (mat == 0) ? wq : (mat == 1) ? wk : wv;
    dst = wcat + (mat << 18);
  }
  float4 v = ((const float4*)src)[off4];
  unsigned long long pk = (unsigned long long)f2h(v.x)
                        | ((unsigned long long)f2h(v.y) << 16)
                        | ((unsigned long long)f2h(v.z) << 32)
                        | ((unsigned long long)f2h(v.w) << 48);
  *(unsigned long long*)(dst + off4 * 4) = pk;
}

// ---------------------------------------------------------------- QKV GEMM
// C[m][n] = sum_k xb[m][k] * wcat[n][k],  M=16384, N=1536, K=512.
// 128x128 tile, BK=64, 4 waves (2x2), 16x16x32 f16 MFMA, double-buffered LDS.
// K output in flash A-frag order: element (t,d) ->
//   ((((b*64 + t>>5)*32 + (d>>4))*32 + (t&31))*2 + ((d>>3)&1))*8 + (d&7)
// V output in flash frag order (R6): ((b*16+kvt)*16 + u)*512*8 ... (see below)
__device__ __forceinline__ void gemm_stage(
    const unsigned short* __restrict__ xb, const unsigned short* __restrict__ wcat,
    char* smem, int buf, int mbase, int nbase, int kt, int wv, int lane, int srcg) {
  char* base = smem + buf * 32768;
  const int kbase = kt * 64;
  if (wv < 2) {
    #pragma unroll
    for (int i = 0; i < 8; ++i) {
      const int blk = wv * 8 + i;
      const int row = blk * 8 + (lane >> 3);
      gload_lds16(xb + (size_t)(mbase + row) * 512 + kbase + srcg, base + blk * 1024);
    }
  } else {
    #pragma unroll
    for (int i = 0; i < 8; ++i) {
      const int blk = (wv - 2) * 8 + i;
      const int row = blk * 8 + (lane >> 3);
      gload_lds16(wcat + (size_t)(nbase + row) * 512 + kbase + srcg, base + 16384 + blk * 1024);
    }
  }
}

__global__ __launch_bounds__(256, 2) void gemm_qkv(
    const unsigned short* __restrict__ xb, const unsigned short* __restrict__ wcat,
    unsigned short* __restrict__ Qb, unsigned short* __restrict__ Kf,
    unsigned short* __restrict__ Vtb) {
  __shared__ char smem[65536];
  const int tid = threadIdx.x, lane = tid & 63, wv = tid >> 6;
  const int wr = wv >> 1, wc = wv & 1;
  const int l15 = lane & 15, l4 = lane >> 4;
  const int mbase = blockIdx.x * 128;
  const int nbase = blockIdx.y * 128;
  const int srcg = (((lane & 7) ^ ((lane >> 3) & 7))) * 8;

  f32x4 acc[4][4];
  #pragma unroll
  for (int i = 0; i < 4; ++i)
    #pragma unroll
    for (int j = 0; j < 4; ++j) acc[i][j] = (f32x4){0.f, 0.f, 0.f, 0.f};

  gemm_stage(xb, wcat, smem, 0, mbase, nbase, 0, wv, lane, srcg);
  for (int kt = 0; kt < 8; ++kt) {
    __syncthreads();
    if (kt < 7) gemm_stage(xb, wcat, smem, (kt + 1) & 1, mbase, nbase, kt + 1, wv, lane, srcg);
    const char* base = smem + (kt & 1) * 32768;
    #pragma unroll
    for (int ks = 0; ks < 2; ++ks) {
      half8 a[4], b8[4];
      #pragma unroll
      for (int rt = 0; rt < 4; ++rt) {
        const int row = wr * 64 + rt * 16 + l15;
        const int G = (ks * 4 + l4) ^ (row & 7);
        a[rt] = *(const half8*)(base + row * 128 + G * 16);
      }
      #pragma unroll
      for (int ct = 0; ct < 4; ++ct) {
        const int row = wc * 64 + ct * 16 + l15;
        const int G = (ks * 4 + l4) ^ (row & 7);
        b8[ct] = *(const half8*)(base + 16384 + row * 128 + G * 16);
      }
      #pragma unroll
      for (int rt = 0; rt < 4; ++rt)
        #pragma unroll
        for (int ct = 0; ct < 4; ++ct)
          acc[rt][ct] = __builtin_amdgcn_mfma_f32_16x16x32_f16(a[rt], b8[ct], acc[rt][ct], 0, 0, 0);
    }
  }

  const int mat = nbase >> 9;          // 0=Q, 1=K, 2=V
  const int nloc = nbase & 511;
  if (mat == 0) {
    #pragma unroll
    for (int rt = 0; rt < 4; ++rt)
      #pragma unroll
      for (int ct = 0; ct < 4; ++ct) {
        const int m0 = mbase + wr * 64 + rt * 16 + l4 * 4;
        const int n = nloc + wc * 64 + ct * 16 + l15;
        #pragma unroll
        for (int j = 0; j < 4; ++j)
          Qb[(size_t)(m0 + j) * 512 + n] = f2h(acc[rt][ct][j]);
      }
  } else if (mat == 1) {
    // K in flash A-frag order
    #pragma unroll
    for (int rt = 0; rt < 4; ++rt)
      #pragma unroll
      for (int ct = 0; ct < 4; ++ct) {
        const int m0 = mbase + wr * 64 + rt * 16 + l4 * 4;
        const int d = nloc + wc * 64 + ct * 16 + l15;
        const int s = d >> 4, hh = (d >> 3) & 1, e = d & 7;
        #pragma unroll
        for (int j = 0; j < 4; ++j) {
          const int t = m0 + j;
          const int bb = t >> 11, tt = t & 2047;
          const size_t blk =
              ((((size_t)bb * 64 + (tt >> 5)) * 32 + s) * 32 + (tt & 31)) * 2 + hh;
          Kf[blk * 8 + e] = f2h(acc[rt][ct][j]);
        }
      }
  } else {
    // V in flash frag order; j..j+3 stay within one 16B block
    #pragma unroll
    for (int rt = 0; rt < 4; ++rt)
      #pragma unroll
      for (int ct = 0; ct < 4; ++ct) {
        const int m0 = mbase + wr * 64 + rt * 16 + l4 * 4;
        const int d = nloc + wc * 64 + ct * 16 + l15;
        const int bb = m0 >> 11, t = m0 & 2047;
        const int kvt = t >> 7, u = (t >> 3) & 15, jj = t & 7;
        unsigned long long pk = (unsigned long long)f2h(acc[rt][ct][0])
                              | ((unsigned long long)f2h(acc[rt][ct][1]) << 16)
                              | ((unsigned long long)f2h(acc[rt][ct][2]) << 32)
                              | ((unsigned long long)f2h(acc[rt][ct][3]) << 48);
        *(unsigned long long*)(Vtb + ((((size_t)bb * 16 + kvt) * 16 + u) * 512 + d) * 8 + jj) = pk;
      }
  }
}

// ---------------------------------------------------------------- flash attention
// 256 WGs x 8 waves; b = blk&7 (XCD), qt = 31-(blk>>3) (64 q-rows, long first).
// nkv = (qt+2)>>1 steps of KVBLK=128.
// QK: wave (qg=wv&1, ks=wv>>1): S^T = mfma32(K_frag_regs, Q_frag_lds), full D.
// PV: wave owns d strip [wv*64..+64): O^T += mfma32(V_frag_global, P_lds).
// Per step (parity p): kf loads -> QK -> mask/max -> stx[p] -> lgkmB ->
//   vf0 loads, softmax, P[p]+sts[p] -> lgkmC -> rescale, vf1, PV.
__global__ __launch_bounds__(512, 1) void flash_kernel(
    const unsigned short* __restrict__ Qb, const unsigned short* __restrict__ Kf,
    const unsigned short* __restrict__ Vtb, float* __restrict__ out) {
  extern __shared__ char smem[];

  const int tid = threadIdx.x, lane = tid & 63, wv = tid >> 6;
  const int l31 = lane & 31, h = lane >> 5;
  const int qg = wv & 1, ks = wv >> 1;             // QK role
  const int dh = wv;                               // PV role d-strip
  const int qsw = l31 & 7;                         // P swizzle (row&7 == l31&7)
  const int b = blockIdx.x & 7;                    // batch == XCD
  const int qt = 31 - (blockIdx.x >> 3);           // long tiles first
  const size_t bT = (size_t)b * T_;
  const int nkv = (qt + 2) >> 1;

  // ---- stage Q [64][512] once: LDS[r] granule g = Q[r][g ^ (r&31)] ----
  {
    const unsigned short* src = Qb + (bT + (size_t)qt * 64) * 512;
    #pragma unroll
    for (int i = 0; i < 8; ++i) {
      const int r = wv * 8 + i;
      gload_lds16(src + (size_t)r * 512 + ((lane ^ (r & 31)) * 8), smem + r * 1024);
    }
  }
  asm volatile("s_waitcnt vmcnt(0)" ::: "memory");
  __builtin_amdgcn_s_barrier();

  f32x16 o[2][2];                                  // o[dt][q2]: O^T [32 d][32 q]
  #pragma unroll
  for (int dt = 0; dt < 2; ++dt)
    #pragma unroll
    for (int q2 = 0; q2 < 2; ++q2)
      #pragma unroll
      for (int r = 0; r < 16; ++r) o[dt][q2][r] = 0.f;
  float lreg[2] = {0.f, 0.f};
  float mqpv[2] = {-1e30f, -1e30f};
  float mqk = -1e30f;

  for (int kv = 0; kv < nkv; ++kv) {
    const int kv0 = kv * 128;
    const int p = kv & 1;
    char* Pp = smem + FL_P + p * 16384;
    float* stxp = (float*)(smem + FL_STX + p * 1024);
    float* stsp = (float*)(smem + FL_STS + p * 1024);

    // ---- K strip -> transient regs: contiguous frag-order loads ----
    half8 kf[32];
    {
      const unsigned short* kp =
          Kf + ((((size_t)b * 64 + (kv * 4 + ks)) << 14)) + l31 * 16 + h * 8;
      #pragma unroll
      for (int s = 0; s < 32; ++s) kf[s] = *(const half8*)(kp + s * 512);
    }

    // ---- QK^T swapped: acc = S^T[32 kv strip][32 q], full D ----
    f32x16 acc;
    #pragma unroll
    for (int r = 0; r < 16; ++r) acc[r] = 0.f;
    {
      const int qrow = qg * 32 + l31;
      const char* qb = smem + qrow * 1024;
      const int qs5 = qrow & 31;
      #pragma unroll
      for (int s = 0; s < 32; ++s) {
        half8 qf = *(const half8*)(qb + (((s * 2 + h) ^ qs5) << 4));
        acc = __builtin_amdgcn_mfma_f32_32x32x16_f16(kf[s], qf, acc, 0, 0, 0);
      }
    }

    // ---- scale + causal mask + in-lane strip max ----
    float v[16], tm = -1e30f;
    const int qglob = qt * 64 + qg * 32 + l31;
    #pragma unroll
    for (int r = 0; r < 16; ++r) {
      const int kvg = kv0 + ks * 32 + (r & 3) + 8 * (r >> 2) + 4 * h;
      v[r] = (kvg <= qglob) ? acc[r] * SCALE_ : -1e30f;
      tm = fmaxf(tm, v[r]);
    }
    tm = fmaxf(tm, __shfl_xor(tm, 32, 64));
    if (h == 0) stxp[(qg * 32 + l31) * 4 + ks] = tm;
    barrier_lgkm();                                // B: strip maxes visible

    // ---- V frags half 0 (s=0..3): contiguous fragment-order loads ----
    const size_t vblk = ((size_t)b * 16 + kv) * 16;
    half8 vf0[4][2];
    #pragma unroll
    for (int s = 0; s < 4; ++s)
      #pragma unroll
      for (int dt = 0; dt < 2; ++dt)
        vf0[s][dt] = *(const half8*)(
            Vtb + ((vblk + s * 2 + h) * 512 + dh * 64 + dt * 32 + l31) * 8);

    // ---- softmax (per-lane scalar state) ----
    {
      const f32x4 sx = *(const f32x4*)(stxp + (qg * 32 + l31) * 4);
      const float mn = fmaxf(fmaxf(fmaxf(sx[0], sx[1]), fmaxf(sx[2], sx[3])), mqk);
      mqk = mn;
      unsigned short ph[16];
      float ps = 0.f;
      #pragma unroll
      for (int r = 0; r < 16; ++r) {
        const float pv = __expf(v[r] - mn);
        ph[r] = f2h(pv);                           // round first; sum the rounded
        ps += (float)*(const _Float16*)&ph[r];
      }
      ps += __shfl_xor(ps, 32, 64);
      if (h == 0) stsp[(qg * 32 + l31) * 4 + ks] = ps;
      #pragma unroll
      for (int c = 0; c < 4; ++c) {                // P -> LDS, b64 packed
        const unsigned long long pk =
            (unsigned long long)ph[4 * c]
          | ((unsigned long long)ph[4 * c + 1] << 16)
          | ((unsigned long long)ph[4 * c + 2] << 32)
          | ((unsigned long long)ph[4 * c + 3] << 48);
        *(unsigned long long*)(Pp + (qg * 32 + l31) * 256 +
                               ((((ks * 4 + c) ^ qsw)) << 4) + h * 8) = pk;
      }
    }
    barrier_lgkm();                                // C: P + stats visible

    // ---- per-lane alpha/l update, rescale O ----
    #pragma unroll
    for (int q2 = 0; q2 < 2; ++q2) {
      const f32x4 sx2 = *(const f32x4*)(stxp + (q2 * 32 + l31) * 4);
      float mn2 = fmaxf(fmaxf(sx2[0], sx2[1]), fmaxf(sx2[2], sx2[3]));
      mn2 = fmaxf(mn2, mqpv[q2]);
      const float a = __expf(mqpv[q2] - mn2);
      mqpv[q2] = mn2;
      const f32x4 s4 = *(const f32x4*)(stsp + (q2 * 32 + l31) * 4);
      lreg[q2] = a * lreg[q2] + ((s4[0] + s4[1]) + (s4[2] + s4[3]));
      #pragma unroll
      for (int dt = 0; dt < 2; ++dt)
        #pragma unroll
        for (int r = 0; r < 16; ++r) o[dt][q2][r] *= a;
    }

    // ---- V frags half 1 (s=4..7) ----
    half8 vf1[4][2];
    #pragma unroll
    for (int s = 0; s < 4; ++s)
      #pragma unroll
      for (int dt = 0; dt < 2; ++dt)
        vf1[s][dt] = *(const half8*)(
            Vtb + ((vblk + (s + 4) * 2 + h) * 512 + dh * 64 + dt * 32 + l31) * 8);

    // ---- PV: O^T += Vt x P ----
    #pragma unroll
    for (int s = 0; s < 8; ++s) {
      half8 pa[2];
      #pragma unroll
      for (int q2 = 0; q2 < 2; ++q2)
        pa[q2] = *(const half8*)(Pp + (q2 * 32 + l31) * 256 +
                                 (((s * 2 + h) ^ qsw) << 4));
      #pragma unroll
      for (int dt = 0; dt < 2; ++dt) {
        const half8 vfr = (s < 4) ? vf0[s][dt] : vf1[s - 4][dt];
        #pragma unroll
        for (int q2 = 0; q2 < 2; ++q2)
          o[dt][q2] = __builtin_amdgcn_mfma_f32_32x32x16_f16(vfr, pa[q2], o[dt][q2], 0, 0, 0);
      }
    }
  }

  // ---- epilogue: transpose O^T via per-wave scratch (Q region is dead), ----
  // ---- divide by l, coalesced 128B stores ----
  {
    char* scr = smem + wv * 4608;                  // 32 rows x 144B
    const float linv[2] = {1.0f / lreg[0], 1.0f / lreg[1]};
    #pragma unroll
    for (int q2 = 0; q2 < 2; ++q2)
      #pragma unroll
      for (int dt = 0; dt < 2; ++dt) {
        #pragma unroll
        for (int c = 0; c < 4; ++c) {
          f32x4 w4;
          #pragma unroll
          for (int j = 0; j < 4; ++j) w4[j] = o[dt][q2][4 * c + j] * linv[q2];
          *(f32x4*)(scr + l31 * 144 + c * 32 + h * 16) = w4;   // scr[q][d]
        }
        asm volatile("s_waitcnt lgkmcnt(0)" ::: "memory");
        #pragma unroll
        for (int g = 0; g < 4; ++g) {
          const int qr = g * 8 + (lane >> 3);
          const f32x4 r4 = *(const f32x4*)(scr + qr * 144 + (lane & 7) * 16);
          *(f32x4*)(out + (bT + qt * 64 + q2 * 32 + qr) * 512 +
                    dh * 64 + dt * 32 + (lane & 7) * 4) = r4;
        }
        asm volatile("s_waitcnt lgkmcnt(0)" ::: "memory");
      }
  }
}

// ---------------------------------------------------------------- launch
extern "C" void kernel_launch(void* const* d_in, const int* in_sizes, int n_in,
                              void* d_out, int out_size, void* d_ws, size_t ws_size,
                              hipStream_t stream) {
  (void)in_sizes; (void)n_in; (void)out_size; (void)ws_size;
  const float* x  = (const float*)d_in[0];
  const float* wq = (const float*)d_in[1];
  const float* wk = (const float*)d_in[2];
  const float* wv = (const float*)d_in[3];
  float* out = (float*)d_out;

  unsigned short* ws   = (unsigned short*)d_ws;
  unsigned short* xb   = ws;                                    // [16384][512]
  unsigned short* wcat = xb + (size_t)16384 * 512;              // [1536][512]
  unsigned short* Qb   = wcat + (size_t)1536 * 512;             // [16384][512] row-major
  unsigned short* Kf   = Qb + (size_t)16384 * 512;              // [8][64][32][32][2][8] frag order
  unsigned short* Vtb  = Kf + (size_t)16384 * 512;              // [8][16][16][512][8] frag order
  // total ws use: 68.7 MB

  cast_kernel<<<8960, 256, 0, stream>>>(x, wq, wk, wv, xb, wcat);
  gemm_qkv<<<dim3(128, 12), 256, 0, stream>>>(xb, wcat, Qb, Kf, Vtb);
  hipFuncSetAttribute(reinterpret_cast<const void*>(flash_kernel),
                      hipFuncAttributeMaxDynamicSharedMemorySize, FL_SMEM);
  flash_kernel<<<256, 512, FL_SMEM, stream>>>(Qb, Kf, Vtb, out);
}